// Round 2
// baseline (541.730 us; speedup 1.0000x reference)
//
#include <hip/hip_runtime.h>
#include <hip/hip_bf16.h>

// Problem constants (B=2, T=512, H=1024, V=50000)
#define M_DIM 1024      // B*T rows
#define K_DIM 1024      // H
#define V_DIM 50000     // vocab (N)
#define NPAD  50048     // Wb rows (multiple of 128; unchanged workspace layout)
#define NT_N  196       // ceil(V/256) N-tiles (last tile over-reads into Ab, cols discarded)
#define NT_M  4         // 1024/256
#define NIT   8         // K / 128 (2 K-tiles of 64 per iteration)
#define WCONV_BLOCKS 25024       // NPAD*K_DIM/8/256
#define ACONV_BLOCKS 512         // M_DIM*K_DIM/8/256

typedef __attribute__((ext_vector_type(8))) short short8;
typedef __attribute__((ext_vector_type(4))) float floatx4;

#define VMCNT(n) asm volatile("s_waitcnt vmcnt(" #n ")" ::: "memory")
#define BAR()    __builtin_amdgcn_s_barrier()
#define CF()     asm volatile("" ::: "memory")

__device__ inline unsigned short f32_to_bf16(float f) {
    unsigned int u = __float_as_uint(f);
    u += 0x7FFF + ((u >> 16) & 1);   // round-to-nearest-even
    return (unsigned short)(u >> 16);
}

__device__ inline void async_copy16(const unsigned short* g, unsigned short* l) {
    __builtin_amdgcn_global_load_lds(
        (const __attribute__((address_space(1))) unsigned int*)g,
        (__attribute__((address_space(3))) unsigned int*)l,
        16, 0, 0);
}

__global__ __launch_bounds__(256) void convert_all_kernel(
    const float* __restrict__ W, const float* __restrict__ hidden,
    unsigned short* __restrict__ Wb, unsigned short* __restrict__ Ab)
{
    const float* src;
    unsigned short* dst;
    size_t n_valid, i;
    if (blockIdx.x < WCONV_BLOCKS) {
        src = W; dst = Wb; n_valid = (size_t)V_DIM * K_DIM;
        i = ((size_t)blockIdx.x * 256 + threadIdx.x) * 8;
    } else {
        src = hidden; dst = Ab; n_valid = (size_t)M_DIM * K_DIM;
        i = ((size_t)(blockIdx.x - WCONV_BLOCKS) * 256 + threadIdx.x) * 8;
    }
    unsigned short h[8];
    if (i < n_valid) {
        const float4* p = (const float4*)(src + i);
        float4 a = p[0], b = p[1];
        h[0] = f32_to_bf16(a.x); h[1] = f32_to_bf16(a.y);
        h[2] = f32_to_bf16(a.z); h[3] = f32_to_bf16(a.w);
        h[4] = f32_to_bf16(b.x); h[5] = f32_to_bf16(b.y);
        h[6] = f32_to_bf16(b.z); h[7] = f32_to_bf16(b.w);
    } else {
        #pragma unroll
        for (int j = 0; j < 8; ++j) h[j] = 0;
    }
    uint4 o;
    o.x = (unsigned)h[0] | ((unsigned)h[1] << 16);
    o.y = (unsigned)h[2] | ((unsigned)h[3] << 16);
    o.z = (unsigned)h[4] | ((unsigned)h[5] << 16);
    o.w = (unsigned)h[6] | ((unsigned)h[7] << 16);
    *(uint4*)(dst + i) = o;
}

// fast softplus(-|x|): log(1+exp(-|x|)) via hw exp/log; abs err ~1e-7.
__device__ __forceinline__ float bce_base(float x) {
    return fmaxf(x, 0.0f) + __logf(1.0f + __expf(-fabsf(x)));
}

template<bool CHECK>
__device__ __forceinline__ float epilogue_store(
    const floatx4 acc[8][4], float* __restrict__ out,
    const int* __restrict__ lab_s, const float* __restrict__ msk_s,
    int bm, int wm8, int wn4, int bn, int lane)
{
    float lsum = 0.0f;
    const int l4 = lane >> 4;
    #pragma unroll
    for (int fi = 0; fi < 8; ++fi) {
        #pragma unroll
        for (int r = 0; r < 4; ++r) {
            const int trow = (wm8 + fi) * 16 + l4 * 4 + r;   // 0..255 in tile
            const int lab  = lab_s[trow];
            const float m  = msk_s[trow];
            float* orow = out + (size_t)(bm * 256 + trow) * V_DIM;
            #pragma unroll
            for (int fj = 0; fj < 4; ++fj) {
                const int gcol = bn * 256 + (wn4 + fj) * 16 + (lane & 15);
                const float x = acc[fi][fj][r];
                if (!CHECK || gcol < V_DIM) {
                    orow[gcol] = x;
                    float c = bce_base(x);
                    if (lab == gcol) c -= x;
                    lsum += c * m;
                }
            }
        }
    }
    return lsum;
}

// 256x256 tile GEMM (A[M,K] x W[N,K]^T), BK=64, 8 waves (2Mx4N), wave=128x64.
// 8-phase schedule, double-buffered LDS (128 KB), counted vmcnt (never 0 in
// main loop), 1 barrier/phase, XOR bank-swizzle, XCD-aware remap, setprio.
//
// Iteration i: buf0 holds tile E=2i, buf1 holds tile O=2i+1.
//   reads: buf0 at P1(Aq0,Bq0) P2(Bq1) P3(Aq1); buf1 at P5,P6,P7 (same).
//   stages: P1:O.A1->buf1  P2:O.B0->buf1  P3:O.B1->buf1  P4:E'.A0->buf0
//           P5:E'.A1->buf0 P6:E'.B0->buf0 P7:E'.B1->buf0 P8:O'.A0->buf1
//   Every region write is >=1 barrier after its last cross-wave read; each
//   wave's own reads complete before its barrier arrival (compiler lgkm +
//   MFMA use precedes barrier).  vmcnt(2) at P1/P5 = newest 1 stage may be
//   outstanding => all halves of the tile about to be read have landed.
__global__ __launch_bounds__(512, 2) void gemm_loss_kernel(
    const unsigned short* __restrict__ Ab,    // [M_DIM][K_DIM] bf16
    const unsigned short* __restrict__ Wb,    // [NPAD][K_DIM] bf16 (zero-padded)
    const int*            __restrict__ labels,// [M_DIM]
    const float*          __restrict__ amask, // [M_DIM]
    float*                __restrict__ out,   // logits [M_DIM][V_DIM]
    double*               __restrict__ loss_acc)
{
    __shared__ __align__(16) unsigned short As0[256 * 64];  // 32 KB
    __shared__ __align__(16) unsigned short As1[256 * 64];
    __shared__ __align__(16) unsigned short Bs0[256 * 64];
    __shared__ __align__(16) unsigned short Bs1[256 * 64];
    __shared__ int   lab_s[256];
    __shared__ float msk_s[256];
    __shared__ float wred[8];

    const int tid  = threadIdx.x;
    const int lane = tid & 63;
    const int wave = tid >> 6;
    const int wm8  = (wave >> 2) * 8;          // wave row (in 16-row frag units)
    const int wn4  = (wave & 3) * 4;           // wave col (in 16-col frag units)

    // XCD-aware bijective remap (784 = 8*98), bm fastest so the 4 blocks
    // sharing one W-tile run back-to-back on the same XCD.
    const int lin  = blockIdx.x;
    const int pair = (lin & 7) * 98 + (lin >> 3);
    const int bm   = pair & 3;                 // 0..3
    const int bn   = pair >> 2;                // 0..195

    if (tid < 256) {
        lab_s[tid] = labels[bm * 256 + tid];
        msk_s[tid] = amask[bm * 256 + tid];
    }

    floatx4 acc[8][4] = {};

    // --- staging: half-tile = 128 rows x 64 cols = 1024 chunks of 16B; each
    // thread owns chunks tid and tid+512 (rows r0 and r0+64, same slot).
    // LDS dest LINEAR; swizzle via pre-swizzled global source: LDS slot
    // (row, sl) holds global chunk sl ^ (row & 7)   (involution).
    const int r0 = tid >> 3;
    const int sw = (tid & 7) ^ (r0 & 7);
    const unsigned short* pA = Ab + (size_t)(bm * 256 + r0) * K_DIM + sw * 8;
    const unsigned short* pB = Wb + (size_t)(bn * 256 + r0) * K_DIM + sw * 8;

    #define STAGE_A(dst, h, t) do { \
        async_copy16(pA + (size_t)(h) * 131072 + (size_t)(t) * 64,         (dst) + (h) * 8192 + tid * 8); \
        async_copy16(pA + (size_t)(h) * 131072 + (size_t)(t) * 64 + 65536, (dst) + (h) * 8192 + 4096 + tid * 8); \
    } while (0)
    #define STAGE_B(dst, h, t) do { \
        async_copy16(pB + (size_t)(h) * 131072 + (size_t)(t) * 64,         (dst) + (h) * 8192 + tid * 8); \
        async_copy16(pB + (size_t)(h) * 131072 + (size_t)(t) * 64 + 65536, (dst) + (h) * 8192 + 4096 + tid * 8); \
    } while (0)

    // --- fragment reads (same XOR on the read side) --------------------------
    const int frowb = (lane & 15) * 128;                 // row byte offset
    const int cs0   = (((lane >> 4) ^ (lane & 7)) << 4); // k-chunk 0 (swizzled)
    const int cs1   = cs0 ^ 64;                          // k-chunk 1
    const char* Ac0 = (const char*)As0;
    const char* Ac1 = (const char*)As1;
    const char* Bc0 = (const char*)Bs0;
    const char* Bc1 = (const char*)Bs1;

    short8 a[4][2], b0[2][2], b1[2][2];

    #define LOAD_A(bufc, QM) do { \
        _Pragma("unroll") \
        for (int ii = 0; ii < 4; ++ii) { \
            const char* _p = (bufc) + (wm8 + (QM) * 4 + ii) * 2048 + frowb; \
            a[ii][0] = *(const short8*)(_p + cs0); \
            a[ii][1] = *(const short8*)(_p + cs1); \
        } } while (0)
    #define LOAD_B(bufc, QN, bb) do { \
        _Pragma("unroll") \
        for (int jj = 0; jj < 2; ++jj) { \
            const char* _p = (bufc) + (wn4 + (QN) * 2 + jj) * 2048 + frowb; \
            bb[jj][0] = *(const short8*)(_p + cs0); \
            bb[jj][1] = *(const short8*)(_p + cs1); \
        } } while (0)
    #define MFMA_Q(QM, QN, bb) do { \
        __builtin_amdgcn_s_setprio(1); \
        _Pragma("unroll") \
        for (int ii = 0; ii < 4; ++ii) \
            _Pragma("unroll") \
            for (int jj = 0; jj < 2; ++jj) { \
                acc[(QM)*4+ii][(QN)*2+jj] = __builtin_amdgcn_mfma_f32_16x16x32_bf16( \
                    a[ii][0], bb[jj][0], acc[(QM)*4+ii][(QN)*2+jj], 0, 0, 0); \
                acc[(QM)*4+ii][(QN)*2+jj] = __builtin_amdgcn_mfma_f32_16x16x32_bf16( \
                    a[ii][1], bb[jj][1], acc[(QM)*4+ii][(QN)*2+jj], 0, 0, 0); \
            } \
        __builtin_amdgcn_s_setprio(0); \
    } while (0)

    // --- prologue: tile0 fully + tile1.A0 (issue order matters for vmcnt) ---
    STAGE_A(As0, 0, 0); STAGE_A(As0, 1, 0);
    STAGE_B(Bs0, 0, 0); STAGE_B(Bs0, 1, 0);
    STAGE_A(As1, 0, 1);

    for (int i = 0; i < NIT - 1; ++i) {
        const int tO = 2 * i + 1, tE2 = 2 * i + 2, tO2 = 2 * i + 3;
        // P1
        VMCNT(2); BAR(); CF();
        STAGE_A(As1, 1, tO);
        LOAD_A(Ac0, 0); LOAD_B(Bc0, 0, b0);
        MFMA_Q(0, 0, b0);
        // P2
        BAR(); CF();
        STAGE_B(Bs1, 0, tO);
        LOAD_B(Bc0, 1, b1);
        MFMA_Q(0, 1, b1);
        // P3
        BAR(); CF();
        STAGE_B(Bs1, 1, tO);
        LOAD_A(Ac0, 1);
        MFMA_Q(1, 0, b0);
        // P4
        BAR(); CF();
        STAGE_A(As0, 0, tE2);
        MFMA_Q(1, 1, b1);
        // P5
        VMCNT(2); BAR(); CF();
        STAGE_A(As0, 1, tE2);
        LOAD_A(Ac1, 0); LOAD_B(Bc1, 0, b0);
        MFMA_Q(0, 0, b0);
        // P6
        BAR(); CF();
        STAGE_B(Bs0, 0, tE2);
        LOAD_B(Bc1, 1, b1);
        MFMA_Q(0, 1, b1);
        // P7
        BAR(); CF();
        STAGE_B(Bs0, 1, tE2);
        LOAD_A(Ac1, 1);
        MFMA_Q(1, 0, b0);
        // P8
        BAR(); CF();
        STAGE_A(As1, 0, tO2);
        MFMA_Q(1, 1, b1);
    }
    // --- peeled last iteration (i = 7; tiles 14/15; no E'/O' stages) --------
    VMCNT(2); BAR(); CF();
    STAGE_A(As1, 1, 15);
    LOAD_A(Ac0, 0); LOAD_B(Bc0, 0, b0);
    MFMA_Q(0, 0, b0);
    BAR(); CF();
    STAGE_B(Bs1, 0, 15);
    LOAD_B(Bc0, 1, b1);
    MFMA_Q(0, 1, b1);
    BAR(); CF();
    STAGE_B(Bs1, 1, 15);
    LOAD_A(Ac0, 1);
    MFMA_Q(1, 0, b0);
    BAR(); CF();
    MFMA_Q(1, 1, b1);
    VMCNT(0); BAR(); CF();          // drain: tile15 halves staged P1-P3 above
    LOAD_A(Ac1, 0); LOAD_B(Bc1, 0, b0);
    MFMA_Q(0, 0, b0);
    BAR(); CF();
    LOAD_B(Bc1, 1, b1);
    MFMA_Q(0, 1, b1);
    BAR(); CF();
    LOAD_A(Ac1, 1);
    MFMA_Q(1, 0, b0);
    BAR(); CF();
    MFMA_Q(1, 1, b1);

    #undef STAGE_A
    #undef STAGE_B
    #undef LOAD_A
    #undef LOAD_B
    #undef MFMA_Q

    // --- epilogue: store logits + BCE loss terms ----------------------------
    float lsum;
    if (bn < NT_N - 1) {
        lsum = epilogue_store<false>(acc, out, lab_s, msk_s, bm, wm8, wn4, bn, lane);
    } else {
        lsum = epilogue_store<true>(acc, out, lab_s, msk_s, bm, wm8, wn4, bn, lane);
    }

    #pragma unroll
    for (int off = 32; off > 0; off >>= 1) lsum += __shfl_down(lsum, off);
    if (lane == 0) wred[wave] = lsum;
    __syncthreads();
    if (tid == 0) {
        double s = 0.0;
        #pragma unroll
        for (int w = 0; w < 8; ++w) s += (double)wred[w];
        atomicAdd(loss_acc, s);
    }
}

__global__ __launch_bounds__(256) void finalize_kernel(
    const float* __restrict__ amask, const double* __restrict__ loss_acc,
    float* __restrict__ out_loss)
{
    __shared__ float red[256];
    float s = 0.0f;
    for (int i = threadIdx.x; i < M_DIM; i += 256) s += amask[i];
    red[threadIdx.x] = s;
    __syncthreads();
    for (int k = 128; k > 0; k >>= 1) {
        if (threadIdx.x < k) red[threadIdx.x] += red[threadIdx.x + k];
        __syncthreads();
    }
    if (threadIdx.x == 0)
        *out_loss = (float)(*loss_acc / (double)red[0]);
}

extern "C" void kernel_launch(void* const* d_in, const int* in_sizes, int n_in,
                              void* d_out, int out_size, void* d_ws, size_t ws_size,
                              hipStream_t stream) {
    const float* hidden = (const float*)d_in[0];  // [2,512,1024] fp32
    const float* W      = (const float*)d_in[1];  // [50000,1024] fp32
    const int*   labels = (const int*)d_in[2];    // [2,512] int
    const float* amask  = (const float*)d_in[3];  // [2,512] fp32
    float* out = (float*)d_out;                   // 51,200,000 logits + 1 loss

    // workspace layout: Wb (bf16, padded) | Ab (bf16) | loss accumulator.
    // NOTE: last N-tile (bn=195) over-reads 127 rows past Wb into Ab; the
    // affected columns (>=50048) are discarded by the CHECK epilogue and the
    // reads stay inside the workspace allocation.
    unsigned short* Wb = (unsigned short*)d_ws;
    unsigned short* Ab = Wb + (size_t)NPAD * K_DIM;
    double* loss_acc   = (double*)(Ab + (size_t)M_DIM * K_DIM);

    hipMemsetAsync(loss_acc, 0, sizeof(double), stream);

    convert_all_kernel<<<WCONV_BLOCKS + ACONV_BLOCKS, 256, 0, stream>>>(W, hidden, Wb, Ab);

    gemm_loss_kernel<<<dim3(NT_M * NT_N), 512, 0, stream>>>(Ab, Wb, labels, amask, out, loss_acc);

    finalize_kernel<<<1, 256, 0, stream>>>(amask, loss_acc, out + (size_t)M_DIM * V_DIM);
}